// Round 11
// baseline (378.017 us; speedup 1.0000x reference)
//
#include <hip/hip_runtime.h>
#include <math.h>

// Problem constants
#define NB    8
#define CIMG  64
#define HH    256
#define WW    256
#define NL    68
#define NP    136          // 2*NL
#define JD    128          // hidden dim
#define NSYS  71           // 68 + 3 rows
#define NCOL  73           // 71 matrix cols + 2 rhs
#define M64P  75           // f64 row pad: 150 dwords % 32 = 22, gcd 2 -> 2-way (free)
#define NCHK  32           // K1 split-K chunks
#define CHUNK4 1536        // float4 per chunk (6144 floats)
#define ROW4  49152        // float4 per K-row (196608/4)

// d_out (f32) layout: warped [0, 33554432), pred [33554432, +1088), norm at 33555520
#define OUT_PRED 33554432
#define OUT_NORM 33555520

// d_ws (float) layout
#define WS_PART 0          // 32*128*8 = 32768 floats
#define WS_NORM 32768      // 8 floats (per-batch sum of disp^2)
#define WS_DST  32784      // 8*136 floats (control points, y/x interleaved)
#define WS_WV   33920      // 8*142 floats (w[68][2] then v[3][2] per batch)

__device__ __forceinline__ double rl_f64(double v, int sl) {
  const int lo = __builtin_amdgcn_readlane(__double2loint(v), sl);
  const int hi = __builtin_amdgcn_readlane(__double2hiint(v), sl);
  return __hiloint2double(hi, lo);
}
__device__ __forceinline__ float rl_f32(float v, int sl) {
  return __int_as_float(__builtin_amdgcn_readlane(__float_as_int(v), sl));
}

// ---------------------------------------------------------------- K1: h partials
__global__ __launch_bounds__(256) void k1_gemv(const float* __restrict__ x,
                                               const float* __restrict__ W1,
                                               float* __restrict__ part) {
  const int jg  = blockIdx.x;   // 0..31 : group of 4 output rows
  const int ch  = blockIdx.y;   // 0..31 : K chunk
  const int tid = threadIdx.x;
  const float4* __restrict__ xv = (const float4*)x;
  const float4* __restrict__ wv = (const float4*)W1;

  float acc[4][8];
#pragma unroll
  for (int a = 0; a < 4; ++a)
#pragma unroll
    for (int b = 0; b < 8; ++b) acc[a][b] = 0.f;

  const int base = ch * CHUNK4;
#pragma unroll
  for (int it = 0; it < 6; ++it) {
    const int k4 = base + it * 256 + tid;
    float4 w[4];
#pragma unroll
    for (int jj = 0; jj < 4; ++jj)
      w[jj] = wv[(size_t)(jg * 4 + jj) * ROW4 + k4];
#pragma unroll
    for (int b = 0; b < 8; ++b) {
      const float4 xr = xv[(size_t)b * ROW4 + k4];
#pragma unroll
      for (int jj = 0; jj < 4; ++jj) {
        acc[jj][b] = fmaf(w[jj].x, xr.x, acc[jj][b]);
        acc[jj][b] = fmaf(w[jj].y, xr.y, acc[jj][b]);
        acc[jj][b] = fmaf(w[jj].z, xr.z, acc[jj][b]);
        acc[jj][b] = fmaf(w[jj].w, xr.w, acc[jj][b]);
      }
    }
  }
  // wave64 reduction
#pragma unroll
  for (int jj = 0; jj < 4; ++jj)
#pragma unroll
    for (int b = 0; b < 8; ++b) {
      float v = acc[jj][b];
      for (int o = 32; o > 0; o >>= 1) v += __shfl_down(v, o, 64);
      acc[jj][b] = v;
    }
  __shared__ float sred[4][32];
  const int lane = tid & 63, wid = tid >> 6;
  if (lane == 0) {
#pragma unroll
    for (int jj = 0; jj < 4; ++jj)
#pragma unroll
      for (int b = 0; b < 8; ++b) sred[wid][jj * 8 + b] = acc[jj][b];
  }
  __syncthreads();
  if (tid < 32) {
    const float s = sred[0][tid] + sred[1][tid] + sred[2][tid] + sred[3][tid];
    const int jj = tid >> 3, b = tid & 7;
    part[((size_t)ch * JD + jg * 4 + jj) * 8 + b] = s;
  }
}

// augmented-system entry (f64), same numerics as rounds 2/4-10
__device__ __forceinline__ double sys_entry(int r, int c,
                                            const float* s_dst,
                                            const float* s_disp) {
  if (r < NL) {
    if (c < NL) {
      const double dy = (double)s_dst[2 * r]     - (double)s_dst[2 * c];
      const double dx = (double)s_dst[2 * r + 1] - (double)s_dst[2 * c + 1];
      const double d2 = dy * dy + dx * dx;
      double v = 0.5 * d2 * log(fmax(d2, 1e-10));
      if (r == c) v += 1e-6;
      return v;
    }
    if (c == 68) return (double)s_dst[2 * r];
    if (c == 69) return (double)s_dst[2 * r + 1];
    if (c == 70) return 1.0;
    return (double)s_disp[2 * r + (c - 71)];   // rhs cols 71,72
  }
  if (c < NL) {
    const int q = r - NL;
    return (q == 0) ? (double)s_dst[2 * c] : (q == 1) ? (double)s_dst[2 * c + 1] : 1.0;
  }
  return 0.0;
}

// ------------------- K2: landmarks + TPS solve. ONE WAVE per batch.
// f32 GE entirely in registers (lane = row; 2x73 f32 = 146 VGPR — fits, unlike
// the f64 292 of r5-r8), partial pivoting via packed-u32 shfl argmax, pivot-row
// broadcast via v_readlane. L and U archived to LDS; f64 matrix built once in
// LDS; TWO mixed-precision refinement steps (f64 residual -> L/U solve) recover
// f64 accuracy (MAGMA dsgesv pattern). No barriers in the 71-step loop.
__global__ __launch_bounds__(64, 1) void k2_land_solve(
    const float* __restrict__ part, const float* __restrict__ scales,
    const float* __restrict__ lmean, const float* __restrict__ b1,
    const float* __restrict__ W2, const float* __restrict__ b2,
    const float* __restrict__ W3, const float* __restrict__ b3,
    float* __restrict__ out, float* __restrict__ ws) {
  const int b = blockIdx.x, lane = threadIdx.x;
  __shared__ float  s_h[JD];
  __shared__ float  s_dst[NP];
  __shared__ float  s_disp[NP];
  __shared__ double M64[NSYS][M64P];  // f64 system (for residuals)
  __shared__ float  Ud[NCOL][72];     // U dump: [col][slot]
  __shared__ float  Lm[NSYS][72];     // multipliers: [step][row]
  __shared__ double yds0[NSYS], yds1[NSYS];
  __shared__ int    s_perm[NSYS];

  // ---- h[b][j] = b1[j] + sum_chunks part
  for (int j = lane; j < JD; j += 64) {
    float s = b1[j];
#pragma unroll 8
    for (int c = 0; c < NCHK; ++c) s += part[((size_t)c * JD + j) * 8 + b];
    s_h[j] = s;
  }
  __syncthreads();

  // ---- pred / disp
  const float scale_b = scales[b];
  for (int i = lane; i < NP; i += 64) {
    const float4* w2 = (const float4*)(W2 + (size_t)i * JD);
    const float4* w3 = (const float4*)(W3 + (size_t)i * JD);
    float a2 = 0.f, a3 = 0.f;
#pragma unroll 8
    for (int k = 0; k < 32; ++k) {
      const float4 u = w2[k], v = w3[k];
      const float h0 = s_h[4 * k], h1 = s_h[4 * k + 1];
      const float h2 = s_h[4 * k + 2], h3 = s_h[4 * k + 3];
      a2 = fmaf(u.x, h0, fmaf(u.y, h1, fmaf(u.z, h2, fmaf(u.w, h3, a2))));
      a3 = fmaf(v.x, h0, fmaf(v.y, h1, fmaf(v.z, h2, fmaf(v.w, h3, a3))));
    }
    const float pred = a2 + b2[i] + lmean[i];
    const float disp = (a3 + b3[i]) * scale_b;
    out[OUT_PRED + b * NP + i] = pred;
    s_dst[i]  = pred + disp;
    s_disp[i] = disp;
  }
  __syncthreads();

  // ---- norm partial + export control points
  {
    float s = 0.f;
    for (int i = lane; i < NP; i += 64) {
      const float d = s_disp[i];
      s = fmaf(d, d, s);
      ws[WS_DST + b * NP + i] = s_dst[i];
    }
    for (int o = 32; o > 0; o >>= 1) s += __shfl_down(s, o, 64);
    if (lane == 0) ws[WS_NORM + b] = s;
  }

  // ---- build: f64 system into LDS, f32 copy into registers
  const int rowA = lane, rowB = lane + 64;
  const bool hasB = (rowB < NSYS);
  float fA[NCOL], fB[NCOL];
#pragma unroll
  for (int c = 0; c < NCOL; ++c) {
    const double eA = sys_entry(rowA, c, s_dst, s_disp);
    M64[rowA][c] = eA;
    fA[c] = (float)eA;
    double eB = 0.0;
    if (hasB) { eB = sys_entry(rowB, c, s_dst, s_disp); M64[rowB][c] = eB; }
    fB[c] = (float)eB;
  }

  // ---- f32 GE, no-swap partial pivoting, register-resident, zero barriers
  float cvA = fA[0], cvB = fB[0];
  bool actA = true, actB = hasB;
  int slotA = 0, slotB = 0;
#pragma unroll 1
  for (int p = 0; p < NSYS; ++p) {
    unsigned ua = actA ? ((__float_as_uint(fabsf(cvA)) & 0xFFFFFF80u) | (unsigned)rowA) : 0u;
    unsigned ub = actB ? ((__float_as_uint(fabsf(cvB)) & 0xFFFFFF80u) | (unsigned)rowB) : 0u;
    unsigned u = ua > ub ? ua : ub;
#pragma unroll
    for (int o = 1; o < 64; o <<= 1) {
      const unsigned v = __shfl_xor(u, o);
      if (v > u) u = v;
    }
    const int piv = __builtin_amdgcn_readfirstlane((int)(u & 0x7Fu));
    const bool pB = piv >= 64;
    const int  pl = pB ? piv - 64 : piv;
    const float pvA = rl_f32(cvA, pl), pvB = rl_f32(cvB, pl);
    const float inv = 1.0f / (pB ? pvB : pvA);
    if (piv == rowA) { actA = false; slotA = p; }
    if (actB && piv == rowB) { actB = false; slotB = p; }
    const float mA = actA ? cvA * inv : 0.0f;   // pivot/frozen rows: m = 0
    const float mB = actB ? cvB * inv : 0.0f;
    Lm[p][lane] = mA;
    if (lane < 7) Lm[p][64 + lane] = mB;
    if (lane == 0) s_perm[p] = piv;

    // update columns (group-guarded; redundant updates of c<=p touch only
    // never-again-read values — bounded, no overflow)
    if (pB) {
#pragma unroll
      for (int g = 0; g < 10; ++g) {
        if (g * 8 + 7 > p) {
#pragma unroll
          for (int cc = 0; cc < 8; ++cc) {
            const int c = g * 8 + cc;
            if (c < NCOL) {
              const float pr = rl_f32(fB[c], pl);
              fA[c] = fmaf(-mA, pr, fA[c]);
              fB[c] = fmaf(-mB, pr, fB[c]);
            }
          }
        }
      }
    } else {
#pragma unroll
      for (int g = 0; g < 10; ++g) {
        if (g * 8 + 7 > p) {
#pragma unroll
          for (int cc = 0; cc < 8; ++cc) {
            const int c = g * 8 + cc;
            if (c < NCOL) {
              const float pr = rl_f32(fA[c], pl);
              fA[c] = fmaf(-mA, pr, fA[c]);
              fB[c] = fmaf(-mB, pr, fB[c]);
            }
          }
        }
      }
    }
    // extract next pivot-column value (static scan, uniform guards)
    const int pn = p + 1;
#pragma unroll
    for (int g = 0; g < 10; ++g) {
      if (pn >= g * 8 && pn < g * 8 + 8) {
#pragma unroll
        for (int cc = 0; cc < 8; ++cc) {
          const int c = g * 8 + cc;
          if (c < NCOL && c == pn) { cvA = fA[c]; cvB = fB[c]; }
        }
      }
    }
  }

  // ---- dump U by slot: Ud[col][slot]
#pragma unroll
  for (int c = 0; c < NCOL; ++c) {
    Ud[c][slotA] = fA[c];
    if (hasB) Ud[c][slotB] = fB[c];
  }
  __syncthreads();

  // ---- back-sub helper (f64 accumulation over f32 U; slot==variable)
  double sol0a, sol1a, sol0b = 0.0, sol1b = 0.0;
  const double diA = 1.0 / (double)Ud[lane][lane];
  const double diB = hasB ? 1.0 / (double)Ud[rowB][rowB] : 1.0;
#define BACKSUB(BB0A, BB1A, BB0B, BB1B, O0A, O1A, O0B, O1B)                     \
  {                                                                             \
    double bb0a = (BB0A), bb1a = (BB1A), bb0b = (BB0B), bb1b = (BB1B);          \
    double acc0a = 0.0, acc1a = 0.0, acc0b = 0.0, acc1b = 0.0;                  \
    double s0a = 0.0, s1a = 0.0, s0b = 0.0, s1b = 0.0;                          \
    _Pragma("unroll 1")                                                         \
    for (int p = NSYS - 1; p >= 0; --p) {                                       \
      const double tA0 = (bb0a - acc0a) * diA;                                  \
      const double tA1 = (bb1a - acc1a) * diA;                                  \
      const double tB0 = (bb0b - acc0b) * diB;                                  \
      const double tB1 = (bb1b - acc1b) * diB;                                  \
      const bool fromB = (p >= 64);                                             \
      const int  src   = fromB ? (p - 64) : p;                                  \
      const double x0 = rl_f64(fromB ? tB0 : tA0, src);                         \
      const double x1 = rl_f64(fromB ? tB1 : tA1, src);                         \
      if (p >= 64) { if (lane == p - 64) { s0b = tB0; s1b = tB1; } }            \
      else         { if (lane == p)      { s0a = tA0; s1a = tA1; } }            \
      if (lane < p) {                                                           \
        const double u2 = (double)Ud[p][lane];                                  \
        acc0a = fma(u2, x0, acc0a);                                             \
        acc1a = fma(u2, x1, acc1a);                                             \
      }                                                                         \
      if (hasB && rowB < p) {                                                   \
        const double u2 = (double)Ud[p][rowB];                                  \
        acc0b = fma(u2, x0, acc0b);                                             \
        acc1b = fma(u2, x1, acc1b);                                             \
      }                                                                         \
    }                                                                           \
    O0A = s0a; O1A = s1a; O0B = s0b; O1B = s1b;                                 \
  }

  BACKSUB((double)Ud[NSYS][lane], (double)Ud[NSYS + 1][lane],
          hasB ? (double)Ud[NSYS][rowB] : 0.0, hasB ? (double)Ud[NSYS + 1][rowB] : 0.0,
          sol0a, sol1a, sol0b, sol1b)

  // ---- two mixed-precision refinement steps (f64 residual, f32 L/U solve)
#pragma unroll 1
  for (int it = 0; it < 2; ++it) {
    // residual r = b - A*x (f64)
    double r0A = M64[rowA][71], r1A = M64[rowA][72];
    double r0B = hasB ? M64[rowB][71] : 0.0;
    double r1B = hasB ? M64[rowB][72] : 0.0;
#pragma unroll 1
    for (int c = 0; c < 64; ++c) {
      const double x0 = rl_f64(sol0a, c), x1 = rl_f64(sol1a, c);
      const double a = M64[rowA][c];
      r0A = fma(-a, x0, r0A); r1A = fma(-a, x1, r1A);
      const double bm = hasB ? M64[rowB][c] : 0.0;
      r0B = fma(-bm, x0, r0B); r1B = fma(-bm, x1, r1B);
    }
#pragma unroll 1
    for (int c = 64; c < NSYS; ++c) {
      const double x0 = rl_f64(sol0b, c - 64), x1 = rl_f64(sol1b, c - 64);
      const double a = M64[rowA][c];
      r0A = fma(-a, x0, r0A); r1A = fma(-a, x1, r1A);
      const double bm = hasB ? M64[rowB][c] : 0.0;
      r0B = fma(-bm, x0, r0B); r1B = fma(-bm, x1, r1B);
    }
    // forward solve L*y = r (replay multipliers; frozen rows have m=0)
#pragma unroll 1
    for (int p = 0; p < NSYS; ++p) {
      const int pvv = __builtin_amdgcn_readfirstlane(s_perm[p]);
      const bool pB2 = pvv >= 64;
      const int  pl2 = pB2 ? pvv - 64 : pvv;
      const double yp0 = pB2 ? rl_f64(r0B, pl2) : rl_f64(r0A, pl2);
      const double yp1 = pB2 ? rl_f64(r1B, pl2) : rl_f64(r1A, pl2);
      const double lA = (double)Lm[p][lane];
      r0A = fma(-lA, yp0, r0A); r1A = fma(-lA, yp1, r1A);
      const double lB = (lane < 7) ? (double)Lm[p][64 + lane] : 0.0;
      r0B = fma(-lB, yp0, r0B); r1B = fma(-lB, yp1, r1B);
    }
    // re-gather y by slot (slot s <- row perm[s])
    yds0[rowA] = r0A; yds1[rowA] = r1A;
    if (hasB) { yds0[rowB] = r0B; yds1[rowB] = r1B; }
    __syncthreads();
    const int prA = s_perm[lane];
    const int prB = hasB ? s_perm[rowB] : 0;
    double d0a, d1a, d0b, d1b;
    BACKSUB(yds0[prA], yds1[prA],
            hasB ? yds0[prB] : 0.0, hasB ? yds1[prB] : 0.0,
            d0a, d1a, d0b, d1b)
    sol0a += d0a; sol1a += d1a; sol0b += d0b; sol1b += d1b;
    __syncthreads();
  }

  // ---- write solution (variable index = slot = lane / lane+64)
  ws[WS_WV + (size_t)b * 142 + 2 * rowA]     = (float)sol0a;
  ws[WS_WV + (size_t)b * 142 + 2 * rowA + 1] = (float)sol1a;
  if (hasB) {
    ws[WS_WV + (size_t)b * 142 + 2 * rowB]     = (float)sol0b;
    ws[WS_WV + (size_t)b * 142 + 2 * rowB + 1] = (float)sol1b;
  }
}

// ------------------------------- K3: fused spline eval + bilinear warp (+norm finalize)
__global__ __launch_bounds__(256) void k3_warp(const float* __restrict__ img,
                                               const float* __restrict__ ws,
                                               float* __restrict__ out) {
  const int orig = blockIdx.x;
  const int wgid = (orig & 7) * 256 + (orig >> 3);   // bijective (2048 % 8 == 0)
  const int b = wgid >> 8, y = wgid & 255;
  const int tid = threadIdx.x;   // = x

  if (orig == 0 && tid == 0) {
    float s = 0.f;
    for (int i = 0; i < NB; ++i) s += sqrtf(ws[WS_NORM + i]);
    out[OUT_NORM] = s * 0.125f;
  }

  __shared__ float s_c[NP], s_w[NP], s_v[6];
  if (tid < NP) {
    s_c[tid] = ws[WS_DST + b * NP + tid];
    s_w[tid] = ws[WS_WV + (size_t)b * 142 + tid];
  }
  if (tid >= NP && tid < NP + 6) s_v[tid - NP] = ws[WS_WV + (size_t)b * 142 + tid];
  __syncthreads();

  const float yf = (float)y, xf = (float)tid;
  float fy = fmaf(s_v[0], yf, fmaf(s_v[2], xf, s_v[4]));
  float fx = fmaf(s_v[1], yf, fmaf(s_v[3], xf, s_v[5]));
#pragma unroll 4
  for (int l = 0; l < NL; ++l) {
    const float dy = yf - s_c[2 * l];
    const float dx = xf - s_c[2 * l + 1];
    const float r  = fmaf(dy, dy, dx * dx);
    const float ph = 0.5f * r * __logf(fmaxf(r, 1e-10f));
    fy = fmaf(s_w[2 * l],     ph, fy);
    fx = fmaf(s_w[2 * l + 1], ph, fx);
  }

  const float qy = fminf(fmaxf(yf - fy, 0.f), 255.f);
  const float qx = fminf(fmaxf(xf - fx, 0.f), 255.f);
  int y0 = (int)floorf(qy); y0 = y0 > 254 ? 254 : y0;
  int x0 = (int)floorf(qx); x0 = x0 > 254 ? 254 : x0;
  const float wy = qy - (float)y0, wx = qx - (float)x0;
  const float w00 = (1.f - wy) * (1.f - wx), w01 = (1.f - wy) * wx;
  const float w10 = wy * (1.f - wx),         w11 = wy * wx;

  const float* p0 = img + (size_t)b * CIMG * 65536 + y0 * 256 + x0;
  const size_t ob = (size_t)b * CIMG * 65536 + (size_t)y * 256 + tid;
#pragma unroll 4
  for (int c = 0; c < CIMG; ++c) {
    const float* p = p0 + (size_t)c * 65536;
    const float v00 = p[0], v01 = p[1], v10 = p[256], v11 = p[257];
    const float val = fmaf(w00, v00, fmaf(w01, v01, fmaf(w10, v10, w11 * v11)));
    __builtin_nontemporal_store(val, &out[ob + (size_t)c * 65536]);
  }
}

// ------------------------------------------------------------------ launcher
extern "C" void kernel_launch(void* const* d_in, const int* in_sizes, int n_in,
                              void* d_out, int out_size, void* d_ws, size_t ws_size,
                              hipStream_t stream) {
  const float* x      = (const float*)d_in[0];
  const float* img    = (const float*)d_in[1];
  const float* scales = (const float*)d_in[2];
  const float* lmean  = (const float*)d_in[3];
  const float* W1     = (const float*)d_in[4];
  const float* b1     = (const float*)d_in[5];
  const float* W2     = (const float*)d_in[6];
  const float* b2     = (const float*)d_in[7];
  const float* W3     = (const float*)d_in[8];
  const float* b3     = (const float*)d_in[9];
  float* out = (float*)d_out;
  float* ws  = (float*)d_ws;

  k1_gemv<<<dim3(32, 32), 256, 0, stream>>>(x, W1, ws + WS_PART);
  k2_land_solve<<<NB, 64, 0, stream>>>(ws + WS_PART, scales, lmean, b1, W2, b2, W3, b3, out, ws);
  k3_warp<<<NB * HH, 256, 0, stream>>>(img, ws, out);
}

// Round 13
// 287.485 us; speedup vs baseline: 1.3149x; 1.3149x over previous
//
#include <hip/hip_runtime.h>
#include <math.h>

// Problem constants
#define NB    8
#define CIMG  64
#define HH    256
#define WW    256
#define NL    68
#define NP    136          // 2*NL
#define JD    128          // hidden dim
#define NSYS  71           // 68 + 3 rows
#define NCOL  73           // 71 matrix cols + 2 rhs
#define M64P  75           // f64 row pad
#define NCHK  32           // K1 split-K chunks
#define CHUNK4 1536        // float4 per chunk (6144 floats)
#define ROW4  49152        // float4 per K-row (196608/4)

// d_out (f32) layout: warped [0, 33554432), pred [33554432, +1088), norm at 33555520
#define OUT_PRED 33554432
#define OUT_NORM 33555520

// d_ws (float) layout
#define WS_PART 0          // 32*128*8 = 32768 floats
#define WS_NORM 32768      // 8 floats (per-batch sum of disp^2)
#define WS_DST  32784      // 8*136 floats (control points, y/x interleaved)
#define WS_WV   33920      // 8*142 floats (w[68][2] then v[3][2] per batch)

__device__ __forceinline__ double rl_f64(double v, int sl) {
  const int lo = __builtin_amdgcn_readlane(__double2loint(v), sl);
  const int hi = __builtin_amdgcn_readlane(__double2hiint(v), sl);
  return __hiloint2double(hi, lo);
}
__device__ __forceinline__ float rl_f32(float v, int sl) {
  return __int_as_float(__builtin_amdgcn_readlane(__float_as_int(v), sl));
}

// ---------------------------------------------------------------- K1: h partials
__global__ __launch_bounds__(256) void k1_gemv(const float* __restrict__ x,
                                               const float* __restrict__ W1,
                                               float* __restrict__ part) {
  const int jg  = blockIdx.x;   // 0..31 : group of 4 output rows
  const int ch  = blockIdx.y;   // 0..31 : K chunk
  const int tid = threadIdx.x;
  const float4* __restrict__ xv = (const float4*)x;
  const float4* __restrict__ wv = (const float4*)W1;

  float acc[4][8];
#pragma unroll
  for (int a = 0; a < 4; ++a)
#pragma unroll
    for (int b = 0; b < 8; ++b) acc[a][b] = 0.f;

  const int base = ch * CHUNK4;
#pragma unroll
  for (int it = 0; it < 6; ++it) {
    const int k4 = base + it * 256 + tid;
    float4 w[4];
#pragma unroll
    for (int jj = 0; jj < 4; ++jj)
      w[jj] = wv[(size_t)(jg * 4 + jj) * ROW4 + k4];
#pragma unroll
    for (int b = 0; b < 8; ++b) {
      const float4 xr = xv[(size_t)b * ROW4 + k4];
#pragma unroll
      for (int jj = 0; jj < 4; ++jj) {
        acc[jj][b] = fmaf(w[jj].x, xr.x, acc[jj][b]);
        acc[jj][b] = fmaf(w[jj].y, xr.y, acc[jj][b]);
        acc[jj][b] = fmaf(w[jj].z, xr.z, acc[jj][b]);
        acc[jj][b] = fmaf(w[jj].w, xr.w, acc[jj][b]);
      }
    }
  }
  // wave64 reduction
#pragma unroll
  for (int jj = 0; jj < 4; ++jj)
#pragma unroll
    for (int b = 0; b < 8; ++b) {
      float v = acc[jj][b];
      for (int o = 32; o > 0; o >>= 1) v += __shfl_down(v, o, 64);
      acc[jj][b] = v;
    }
  __shared__ float sred[4][32];
  const int lane = tid & 63, wid = tid >> 6;
  if (lane == 0) {
#pragma unroll
    for (int jj = 0; jj < 4; ++jj)
#pragma unroll
      for (int b = 0; b < 8; ++b) sred[wid][jj * 8 + b] = acc[jj][b];
  }
  __syncthreads();
  if (tid < 32) {
    const float s = sred[0][tid] + sred[1][tid] + sred[2][tid] + sred[3][tid];
    const int jj = tid >> 3, b = tid & 7;
    part[((size_t)ch * JD + jg * 4 + jj) * 8 + b] = s;
  }
}

// augmented-system entry (f64), same numerics as rounds 2/4-11
__device__ __forceinline__ double sys_entry(int r, int c,
                                            const float* s_dst,
                                            const float* s_disp) {
  if (r < NL) {
    if (c < NL) {
      const double dy = (double)s_dst[2 * r]     - (double)s_dst[2 * c];
      const double dx = (double)s_dst[2 * r + 1] - (double)s_dst[2 * c + 1];
      const double d2 = dy * dy + dx * dx;
      double v = 0.5 * d2 * log(fmax(d2, 1e-10));
      if (r == c) v += 1e-6;
      return v;
    }
    if (c == 68) return (double)s_dst[2 * r];
    if (c == 69) return (double)s_dst[2 * r + 1];
    if (c == 70) return 1.0;
    return (double)s_disp[2 * r + (c - 71)];   // rhs cols 71,72
  }
  if (c < NL) {
    const int q = r - NL;
    return (q == 0) ? (double)s_dst[2 * c] : (q == 1) ? (double)s_dst[2 * c + 1] : 1.0;
  }
  return 0.0;
}

// 8-wide repeat helpers (literal tokens so ## concatenation works)
#define R8(X,i0,i1,i2,i3,i4,i5,i6,i7) X(i0) X(i1) X(i2) X(i3) X(i4) X(i5) X(i6) X(i7)
#define REP73(X) \
  R8(X,0,1,2,3,4,5,6,7) R8(X,8,9,10,11,12,13,14,15) R8(X,16,17,18,19,20,21,22,23) \
  R8(X,24,25,26,27,28,29,30,31) R8(X,32,33,34,35,36,37,38,39) \
  R8(X,40,41,42,43,44,45,46,47) R8(X,48,49,50,51,52,53,54,55) \
  R8(X,56,57,58,59,60,61,62,63) R8(X,64,65,66,67,68,69,70,71) X(72)
// grouped (guarded) application: skip groups fully inside the eliminated region
#define GELIM_A(i0,i1,i2,i3,i4,i5,i6,i7) if (i7 > p) { R8(E1A,i0,i1,i2,i3,i4,i5,i6,i7) }
#define GELIM_B(i0,i1,i2,i3,i4,i5,i6,i7) if (i7 > p) { R8(E1B,i0,i1,i2,i3,i4,i5,i6,i7) }
#define GEXTR(i0,i1,i2,i3,i4,i5,i6,i7) if (pn >= i0 && pn <= i7) { R8(X1,i0,i1,i2,i3,i4,i5,i6,i7) }
#define ALLG(G) \
  G(0,1,2,3,4,5,6,7) G(8,9,10,11,12,13,14,15) G(16,17,18,19,20,21,22,23) \
  G(24,25,26,27,28,29,30,31) G(32,33,34,35,36,37,38,39) \
  G(40,41,42,43,44,45,46,47) G(48,49,50,51,52,53,54,55) \
  G(56,57,58,59,60,61,62,63) G(64,65,66,67,68,69,70,71)

// ------------------- K2: landmarks + TPS solve. ONE WAVE per batch.
// f32 GE in NAMED SCALAR registers gA0..gA72 / gB0..gB72 (146 f32), packed-u32
// shfl argmax, pivot-row broadcast via v_readlane, L/U archived to LDS, two f64
// mixed-precision refinement steps (r11's verified numerics). Zero barriers in
// the 71-step loop. r12 BUGFIX: column 72's update is applied exactly ONCE
// (r12's R8(...,72x8) applied it 8 times -> corrupted x-flow rhs).
__global__ __launch_bounds__(64, 1) void k2_land_solve(
    const float* __restrict__ part, const float* __restrict__ scales,
    const float* __restrict__ lmean, const float* __restrict__ b1,
    const float* __restrict__ W2, const float* __restrict__ b2,
    const float* __restrict__ W3, const float* __restrict__ b3,
    float* __restrict__ out, float* __restrict__ ws) {
  const int b = blockIdx.x, lane = threadIdx.x;
  __shared__ float  s_h[JD];
  __shared__ float  s_dst[NP];
  __shared__ float  s_disp[NP];
  __shared__ double M64[NSYS][M64P];  // f64 system (for residuals)
  __shared__ float  Ud[NCOL][72];     // U dump: [col][slot]
  __shared__ float  Lm[NSYS][72];     // multipliers: [step][row]
  __shared__ double yds0[NSYS], yds1[NSYS];
  __shared__ int    s_perm[NSYS];

  // ---- h[b][j] = b1[j] + sum_chunks part
  for (int j = lane; j < JD; j += 64) {
    float s = b1[j];
#pragma unroll 8
    for (int c = 0; c < NCHK; ++c) s += part[((size_t)c * JD + j) * 8 + b];
    s_h[j] = s;
  }
  __syncthreads();

  // ---- pred / disp
  const float scale_b = scales[b];
  for (int i = lane; i < NP; i += 64) {
    const float4* w2 = (const float4*)(W2 + (size_t)i * JD);
    const float4* w3 = (const float4*)(W3 + (size_t)i * JD);
    float a2 = 0.f, a3 = 0.f;
#pragma unroll 8
    for (int k = 0; k < 32; ++k) {
      const float4 u = w2[k], v = w3[k];
      const float h0 = s_h[4 * k], h1 = s_h[4 * k + 1];
      const float h2 = s_h[4 * k + 2], h3 = s_h[4 * k + 3];
      a2 = fmaf(u.x, h0, fmaf(u.y, h1, fmaf(u.z, h2, fmaf(u.w, h3, a2))));
      a3 = fmaf(v.x, h0, fmaf(v.y, h1, fmaf(v.z, h2, fmaf(v.w, h3, a3))));
    }
    const float pred = a2 + b2[i] + lmean[i];
    const float disp = (a3 + b3[i]) * scale_b;
    out[OUT_PRED + b * NP + i] = pred;
    s_dst[i]  = pred + disp;
    s_disp[i] = disp;
  }
  __syncthreads();

  // ---- norm partial + export control points
  {
    float s = 0.f;
    for (int i = lane; i < NP; i += 64) {
      const float d = s_disp[i];
      s = fmaf(d, d, s);
      ws[WS_DST + b * NP + i] = s_dst[i];
    }
    for (int o = 32; o > 0; o >>= 1) s += __shfl_down(s, o, 64);
    if (lane == 0) ws[WS_NORM + b] = s;
  }

  // ---- build f64 system into LDS (64 lanes cooperative)
  for (int e = lane; e < NSYS * NCOL; e += 64) {
    const int r = e / NCOL, c = e - r * NCOL;
    M64[r][c] = sys_entry(r, c, s_dst, s_disp);
  }
  __syncthreads();

  // ---- f32 copies into named scalar registers (lane = rows lane, lane+64)
  const int rowA = lane, rowB = lane + 64;
  const bool hasB = (rowB < NSYS);
#define DCL(i) float gA##i, gB##i;
  REP73(DCL)
#undef DCL
#define BLD(i) { gA##i = (float)M64[rowA][i]; gB##i = hasB ? (float)M64[rowB][i] : 0.0f; }
  REP73(BLD)
#undef BLD

  // ---- f32 GE, no-swap partial pivoting, register-resident, zero barriers
  float cvA = gA0, cvB = gB0;
  bool actA = true, actB = hasB;
  int slotA = 0, slotB = 0;
#pragma unroll 1
  for (int p = 0; p < NSYS; ++p) {
    unsigned ua = actA ? ((__float_as_uint(fabsf(cvA)) & 0xFFFFFF80u) | (unsigned)rowA) : 0u;
    unsigned ub = actB ? ((__float_as_uint(fabsf(cvB)) & 0xFFFFFF80u) | (unsigned)rowB) : 0u;
    unsigned u = ua > ub ? ua : ub;
#pragma unroll
    for (int o = 1; o < 64; o <<= 1) {
      const unsigned v = __shfl_xor(u, o);
      if (v > u) u = v;
    }
    const int piv = __builtin_amdgcn_readfirstlane((int)(u & 0x7Fu));
    const bool pB = piv >= 64;
    const int  pl = pB ? piv - 64 : piv;
    const float pvA = rl_f32(cvA, pl), pvB = rl_f32(cvB, pl);
    const float inv = 1.0f / (pB ? pvB : pvA);
    if (piv == rowA) { actA = false; slotA = p; }
    if (actB && piv == rowB) { actB = false; slotB = p; }
    const float mA = actA ? cvA * inv : 0.0f;   // pivot/frozen rows: m = 0
    const float mB = actB ? cvB * inv : 0.0f;
    Lm[p][lane] = mA;
    if (lane < 7) Lm[p][64 + lane] = mB;
    if (lane == 0) s_perm[p] = piv;

    // rank-1 update; groups fully in the eliminated region are skipped.
    // Column 72 updated exactly once (r12 bug was 8x here).
#define E1A(i) { const float pr = rl_f32(gA##i, pl); \
      gA##i = fmaf(-mA, pr, gA##i); gB##i = fmaf(-mB, pr, gB##i); }
#define E1B(i) { const float pr = rl_f32(gB##i, pl); \
      gA##i = fmaf(-mA, pr, gA##i); gB##i = fmaf(-mB, pr, gB##i); }
    if (pB) { ALLG(GELIM_B) E1B(72) }
    else    { ALLG(GELIM_A) E1A(72) }
#undef E1A
#undef E1B

    // extract next pivot-column value (literal-indexed, group-guarded)
    const int pn = p + 1;
#define X1(i) if (pn == i) { cvA = gA##i; cvB = gB##i; }
    ALLG(GEXTR)
    X1(72)
#undef X1
  }

  // ---- dump U by slot: Ud[col][slot]
#define DMP(i) { Ud[i][slotA] = gA##i; if (hasB) Ud[i][slotB] = gB##i; }
  REP73(DMP)
#undef DMP
  __syncthreads();

  // ---- back-sub (f64 accumulation over f32 U; slot == variable)
  double sol0a, sol1a, sol0b = 0.0, sol1b = 0.0;
  const double diA = 1.0 / (double)Ud[lane][lane];
  const double diB = hasB ? 1.0 / (double)Ud[rowB][rowB] : 1.0;
#define BACKSUB(BB0A, BB1A, BB0B, BB1B, O0A, O1A, O0B, O1B)                     \
  {                                                                             \
    double bb0a = (BB0A), bb1a = (BB1A), bb0b = (BB0B), bb1b = (BB1B);          \
    double acc0a = 0.0, acc1a = 0.0, acc0b = 0.0, acc1b = 0.0;                  \
    double s0a = 0.0, s1a = 0.0, s0b = 0.0, s1b = 0.0;                          \
    _Pragma("unroll 1")                                                         \
    for (int p = NSYS - 1; p >= 0; --p) {                                       \
      const double tA0 = (bb0a - acc0a) * diA;                                  \
      const double tA1 = (bb1a - acc1a) * diA;                                  \
      const double tB0 = (bb0b - acc0b) * diB;                                  \
      const double tB1 = (bb1b - acc1b) * diB;                                  \
      const bool fromB = (p >= 64);                                             \
      const int  src   = fromB ? (p - 64) : p;                                  \
      const double x0 = rl_f64(fromB ? tB0 : tA0, src);                         \
      const double x1 = rl_f64(fromB ? tB1 : tA1, src);                         \
      if (p >= 64) { if (lane == p - 64) { s0b = tB0; s1b = tB1; } }            \
      else         { if (lane == p)      { s0a = tA0; s1a = tA1; } }            \
      if (lane < p) {                                                           \
        const double u2 = (double)Ud[p][lane];                                  \
        acc0a = fma(u2, x0, acc0a);                                             \
        acc1a = fma(u2, x1, acc1a);                                             \
      }                                                                         \
      if (hasB && rowB < p) {                                                   \
        const double u2 = (double)Ud[p][rowB];                                  \
        acc0b = fma(u2, x0, acc0b);                                             \
        acc1b = fma(u2, x1, acc1b);                                             \
      }                                                                         \
    }                                                                           \
    O0A = s0a; O1A = s1a; O0B = s0b; O1B = s1b;                                 \
  }

  BACKSUB((double)Ud[NSYS][lane], (double)Ud[NSYS + 1][lane],
          hasB ? (double)Ud[NSYS][rowB] : 0.0, hasB ? (double)Ud[NSYS + 1][rowB] : 0.0,
          sol0a, sol1a, sol0b, sol1b)

  // ---- two mixed-precision refinement steps (f64 residual, f32 L/U solve)
#pragma unroll 1
  for (int it = 0; it < 2; ++it) {
    double r0A = M64[rowA][71], r1A = M64[rowA][72];
    double r0B = hasB ? M64[rowB][71] : 0.0;
    double r1B = hasB ? M64[rowB][72] : 0.0;
#pragma unroll 1
    for (int c = 0; c < 64; ++c) {
      const double x0 = rl_f64(sol0a, c), x1 = rl_f64(sol1a, c);
      const double a = M64[rowA][c];
      r0A = fma(-a, x0, r0A); r1A = fma(-a, x1, r1A);
      const double bm = hasB ? M64[rowB][c] : 0.0;
      r0B = fma(-bm, x0, r0B); r1B = fma(-bm, x1, r1B);
    }
#pragma unroll 1
    for (int c = 64; c < NSYS; ++c) {
      const double x0 = rl_f64(sol0b, c - 64), x1 = rl_f64(sol1b, c - 64);
      const double a = M64[rowA][c];
      r0A = fma(-a, x0, r0A); r1A = fma(-a, x1, r1A);
      const double bm = hasB ? M64[rowB][c] : 0.0;
      r0B = fma(-bm, x0, r0B); r1B = fma(-bm, x1, r1B);
    }
    // forward solve L*y = r (replay multipliers; frozen rows have m=0)
#pragma unroll 1
    for (int p = 0; p < NSYS; ++p) {
      const int pvv = __builtin_amdgcn_readfirstlane(s_perm[p]);
      const bool pB2 = pvv >= 64;
      const int  pl2 = pB2 ? pvv - 64 : pvv;
      const double yp0 = pB2 ? rl_f64(r0B, pl2) : rl_f64(r0A, pl2);
      const double yp1 = pB2 ? rl_f64(r1B, pl2) : rl_f64(r1A, pl2);
      const double lA = (double)Lm[p][lane];
      r0A = fma(-lA, yp0, r0A); r1A = fma(-lA, yp1, r1A);
      const double lB = (lane < 7) ? (double)Lm[p][64 + lane] : 0.0;
      r0B = fma(-lB, yp0, r0B); r1B = fma(-lB, yp1, r1B);
    }
    yds0[rowA] = r0A; yds1[rowA] = r1A;
    if (hasB) { yds0[rowB] = r0B; yds1[rowB] = r1B; }
    __syncthreads();
    const int prA = s_perm[lane];
    const int prB = hasB ? s_perm[rowB] : 0;
    double d0a, d1a, d0b, d1b;
    BACKSUB(yds0[prA], yds1[prA],
            hasB ? yds0[prB] : 0.0, hasB ? yds1[prB] : 0.0,
            d0a, d1a, d0b, d1b)
    sol0a += d0a; sol1a += d1a; sol0b += d0b; sol1b += d1b;
    __syncthreads();
  }

  // ---- write solution (variable index = slot = lane / lane+64)
  ws[WS_WV + (size_t)b * 142 + 2 * rowA]     = (float)sol0a;
  ws[WS_WV + (size_t)b * 142 + 2 * rowA + 1] = (float)sol1a;
  if (hasB) {
    ws[WS_WV + (size_t)b * 142 + 2 * rowB]     = (float)sol0b;
    ws[WS_WV + (size_t)b * 142 + 2 * rowB + 1] = (float)sol1b;
  }
}

// ------------------------------- K3: fused spline eval + bilinear warp (+norm finalize)
__global__ __launch_bounds__(256) void k3_warp(const float* __restrict__ img,
                                               const float* __restrict__ ws,
                                               float* __restrict__ out) {
  const int orig = blockIdx.x;
  const int wgid = (orig & 7) * 256 + (orig >> 3);   // bijective (2048 % 8 == 0)
  const int b = wgid >> 8, y = wgid & 255;
  const int tid = threadIdx.x;   // = x

  if (orig == 0 && tid == 0) {
    float s = 0.f;
    for (int i = 0; i < NB; ++i) s += sqrtf(ws[WS_NORM + i]);
    out[OUT_NORM] = s * 0.125f;
  }

  __shared__ float s_c[NP], s_w[NP], s_v[6];
  if (tid < NP) {
    s_c[tid] = ws[WS_DST + b * NP + tid];
    s_w[tid] = ws[WS_WV + (size_t)b * 142 + tid];
  }
  if (tid >= NP && tid < NP + 6) s_v[tid - NP] = ws[WS_WV + (size_t)b * 142 + tid];
  __syncthreads();

  const float yf = (float)y, xf = (float)tid;
  float fy = fmaf(s_v[0], yf, fmaf(s_v[2], xf, s_v[4]));
  float fx = fmaf(s_v[1], yf, fmaf(s_v[3], xf, s_v[5]));
#pragma unroll 4
  for (int l = 0; l < NL; ++l) {
    const float dy = yf - s_c[2 * l];
    const float dx = xf - s_c[2 * l + 1];
    const float r  = fmaf(dy, dy, dx * dx);
    const float ph = 0.5f * r * __logf(fmaxf(r, 1e-10f));
    fy = fmaf(s_w[2 * l],     ph, fy);
    fx = fmaf(s_w[2 * l + 1], ph, fx);
  }

  const float qy = fminf(fmaxf(yf - fy, 0.f), 255.f);
  const float qx = fminf(fmaxf(xf - fx, 0.f), 255.f);
  int y0 = (int)floorf(qy); y0 = y0 > 254 ? 254 : y0;
  int x0 = (int)floorf(qx); x0 = x0 > 254 ? 254 : x0;
  const float wy = qy - (float)y0, wx = qx - (float)x0;
  const float w00 = (1.f - wy) * (1.f - wx), w01 = (1.f - wy) * wx;
  const float w10 = wy * (1.f - wx),         w11 = wy * wx;

  const float* p0 = img + (size_t)b * CIMG * 65536 + y0 * 256 + x0;
  const size_t ob = (size_t)b * CIMG * 65536 + (size_t)y * 256 + tid;
#pragma unroll 4
  for (int c = 0; c < CIMG; ++c) {
    const float* p = p0 + (size_t)c * 65536;
    const float v00 = p[0], v01 = p[1], v10 = p[256], v11 = p[257];
    const float val = fmaf(w00, v00, fmaf(w01, v01, fmaf(w10, v10, w11 * v11)));
    __builtin_nontemporal_store(val, &out[ob + (size_t)c * 65536]);
  }
}

// ------------------------------------------------------------------ launcher
extern "C" void kernel_launch(void* const* d_in, const int* in_sizes, int n_in,
                              void* d_out, int out_size, void* d_ws, size_t ws_size,
                              hipStream_t stream) {
  const float* x      = (const float*)d_in[0];
  const float* img    = (const float*)d_in[1];
  const float* scales = (const float*)d_in[2];
  const float* lmean  = (const float*)d_in[3];
  const float* W1     = (const float*)d_in[4];
  const float* b1     = (const float*)d_in[5];
  const float* W2     = (const float*)d_in[6];
  const float* b2     = (const float*)d_in[7];
  const float* W3     = (const float*)d_in[8];
  const float* b3     = (const float*)d_in[9];
  float* out = (float*)d_out;
  float* ws  = (float*)d_ws;

  k1_gemv<<<dim3(32, 32), 256, 0, stream>>>(x, W1, ws + WS_PART);
  k2_land_solve<<<NB, 64, 0, stream>>>(ws + WS_PART, scales, lmean, b1, W2, b2, W3, b3, out, ws);
  k3_warp<<<NB * HH, 256, 0, stream>>>(img, ws, out);
}

// Round 14
// 241.840 us; speedup vs baseline: 1.5631x; 1.1887x over previous
//
#include <hip/hip_runtime.h>
#include <math.h>

// Problem constants
#define NB    8
#define CIMG  64
#define HH    256
#define WW    256
#define NL    68
#define NP    136          // 2*NL
#define JD    128          // hidden dim
#define NSYS  71           // 68 + 3 rows
#define NCOL  73           // 71 matrix cols + 2 rhs
#define SEG   19           // columns per wave (4 waves: 19+19+19+16)
#define M64P  75           // f64 row pad
#define NCHK  32           // K1 split-K chunks
#define CHUNK4 1536        // float4 per chunk (6144 floats)
#define ROW4  49152        // float4 per K-row (196608/4)

// d_out (f32) layout: warped [0, 33554432), pred [33554432, +1088), norm at 33555520
#define OUT_PRED 33554432
#define OUT_NORM 33555520

// d_ws (float) layout
#define WS_PART 0          // 32*128*8 = 32768 floats
#define WS_NORM 32768      // 8 floats (per-batch sum of disp^2)
#define WS_DST  32784      // 8*136 floats (control points, y/x interleaved)
#define WS_WV   33920      // 8*142 floats (w[68][2] then v[3][2] per batch)

__device__ __forceinline__ double rl_f64(double v, int sl) {
  const int lo = __builtin_amdgcn_readlane(__double2loint(v), sl);
  const int hi = __builtin_amdgcn_readlane(__double2hiint(v), sl);
  return __hiloint2double(hi, lo);
}
__device__ __forceinline__ float rl_f32(float v, int sl) {
  return __int_as_float(__builtin_amdgcn_readlane(__float_as_int(v), sl));
}

// ---------------------------------------------------------------- K1: h partials
__global__ __launch_bounds__(256) void k1_gemv(const float* __restrict__ x,
                                               const float* __restrict__ W1,
                                               float* __restrict__ part) {
  const int jg  = blockIdx.x;   // 0..31 : group of 4 output rows
  const int ch  = blockIdx.y;   // 0..31 : K chunk
  const int tid = threadIdx.x;
  const float4* __restrict__ xv = (const float4*)x;
  const float4* __restrict__ wv = (const float4*)W1;

  float acc[4][8];
#pragma unroll
  for (int a = 0; a < 4; ++a)
#pragma unroll
    for (int b = 0; b < 8; ++b) acc[a][b] = 0.f;

  const int base = ch * CHUNK4;
#pragma unroll
  for (int it = 0; it < 6; ++it) {
    const int k4 = base + it * 256 + tid;
    float4 w[4];
#pragma unroll
    for (int jj = 0; jj < 4; ++jj)
      w[jj] = wv[(size_t)(jg * 4 + jj) * ROW4 + k4];
#pragma unroll
    for (int b = 0; b < 8; ++b) {
      const float4 xr = xv[(size_t)b * ROW4 + k4];
#pragma unroll
      for (int jj = 0; jj < 4; ++jj) {
        acc[jj][b] = fmaf(w[jj].x, xr.x, acc[jj][b]);
        acc[jj][b] = fmaf(w[jj].y, xr.y, acc[jj][b]);
        acc[jj][b] = fmaf(w[jj].z, xr.z, acc[jj][b]);
        acc[jj][b] = fmaf(w[jj].w, xr.w, acc[jj][b]);
      }
    }
  }
  // wave64 reduction
#pragma unroll
  for (int jj = 0; jj < 4; ++jj)
#pragma unroll
    for (int b = 0; b < 8; ++b) {
      float v = acc[jj][b];
      for (int o = 32; o > 0; o >>= 1) v += __shfl_down(v, o, 64);
      acc[jj][b] = v;
    }
  __shared__ float sred[4][32];
  const int lane = tid & 63, wid = tid >> 6;
  if (lane == 0) {
#pragma unroll
    for (int jj = 0; jj < 4; ++jj)
#pragma unroll
      for (int b = 0; b < 8; ++b) sred[wid][jj * 8 + b] = acc[jj][b];
  }
  __syncthreads();
  if (tid < 32) {
    const float s = sred[0][tid] + sred[1][tid] + sred[2][tid] + sred[3][tid];
    const int jj = tid >> 3, b = tid & 7;
    part[((size_t)ch * JD + jg * 4 + jj) * 8 + b] = s;
  }
}

// augmented-system entry (f64), same numerics as rounds 2/4-13
__device__ __forceinline__ double sys_entry(int r, int c,
                                            const float* s_dst,
                                            const float* s_disp) {
  if (r < NL) {
    if (c < NL) {
      const double dy = (double)s_dst[2 * r]     - (double)s_dst[2 * c];
      const double dx = (double)s_dst[2 * r + 1] - (double)s_dst[2 * c + 1];
      const double d2 = dy * dy + dx * dx;
      double v = 0.5 * d2 * log(fmax(d2, 1e-10));
      if (r == c) v += 1e-6;
      return v;
    }
    if (c == 68) return (double)s_dst[2 * r];
    if (c == 69) return (double)s_dst[2 * r + 1];
    if (c == 70) return 1.0;
    return (double)s_disp[2 * r + (c - 71)];   // rhs cols 71,72
  }
  if (c < NL) {
    const int q = r - NL;
    return (q == 0) ? (double)s_dst[2 * c] : (q == 1) ? (double)s_dst[2 * c + 1] : 1.0;
  }
  return 0.0;
}

#define REP19(X) X(0) X(1) X(2) X(3) X(4) X(5) X(6) X(7) X(8) X(9) \
                 X(10) X(11) X(12) X(13) X(14) X(15) X(16) X(17) X(18)

// ------------------- K2: landmarks + TPS solve. 4 WAVES per batch.
// f32 GE, column-sharded: wave wv holds ALL 71 rows of columns [wv*19, wv*19+19)
// as NAMED f32 scalars (38 regs — fits even the default 68-VGPR budget; the
// r6/r7 spills were f64's 76 regs). Owner wave (wv == p/SEG) does the packed
// argmax + publishes per-row multipliers through Lm[p][row] (double-buffered by
// step index, and Lm IS the refinement L-archive) + s_piv[p&1]. ONE barrier per
// step. After GE: r13's verified f64 mixed-precision refinement (run redundantly
// by all 4 waves so __syncthreads stays unconditional).
__global__ __launch_bounds__(256) void k2_land_solve(
    const float* __restrict__ part, const float* __restrict__ scales,
    const float* __restrict__ lmean, const float* __restrict__ b1,
    const float* __restrict__ W2, const float* __restrict__ b2,
    const float* __restrict__ W3, const float* __restrict__ b3,
    float* __restrict__ out, float* __restrict__ ws) {
  const int b = blockIdx.x, tid = threadIdx.x;
  const int lane = tid & 63, wv = tid >> 6;
  __shared__ float  s_h[JD];
  __shared__ float  s_dst[NP];
  __shared__ float  s_disp[NP];
  __shared__ double M64[NSYS][M64P];  // f64 system (for residuals)
  __shared__ float  Ud[NCOL][72];     // U dump: [col][slot]
  __shared__ float  Lm[NSYS][72];     // multipliers: [step][row] (publish + archive)
  __shared__ double yds0[NSYS], yds1[NSYS];
  __shared__ int    s_perm[NSYS];
  __shared__ int    s_piv[2];

  // ---- h[b][j] = b1[j] + sum_chunks part
  if (tid < JD) {
    float s = b1[tid];
#pragma unroll 8
    for (int c = 0; c < NCHK; ++c) s += part[((size_t)c * JD + tid) * 8 + b];
    s_h[tid] = s;
  }
  __syncthreads();

  // ---- pred / disp
  const float scale_b = scales[b];
  if (tid < NP) {
    const float4* w2 = (const float4*)(W2 + (size_t)tid * JD);
    const float4* w3 = (const float4*)(W3 + (size_t)tid * JD);
    float a2 = 0.f, a3 = 0.f;
#pragma unroll 8
    for (int k = 0; k < 32; ++k) {
      const float4 u = w2[k], v = w3[k];
      const float h0 = s_h[4 * k], h1 = s_h[4 * k + 1];
      const float h2 = s_h[4 * k + 2], h3 = s_h[4 * k + 3];
      a2 = fmaf(u.x, h0, fmaf(u.y, h1, fmaf(u.z, h2, fmaf(u.w, h3, a2))));
      a3 = fmaf(v.x, h0, fmaf(v.y, h1, fmaf(v.z, h2, fmaf(v.w, h3, a3))));
    }
    const float pred = a2 + b2[tid] + lmean[tid];
    const float disp = (a3 + b3[tid]) * scale_b;
    out[OUT_PRED + b * NP + tid] = pred;
    s_dst[tid]  = pred + disp;
    s_disp[tid] = disp;
  }
  __syncthreads();

  // ---- norm partial + export control points
  if (tid < 64) {
    float s = 0.f;
    for (int i = tid; i < NP; i += 64) { const float d = s_disp[i]; s = fmaf(d, d, s); }
    for (int o = 32; o > 0; o >>= 1) s += __shfl_down(s, o, 64);
    if (tid == 0) ws[WS_NORM + b] = s;
  }
  if (tid < NP) ws[WS_DST + b * NP + tid] = s_dst[tid];

  // ---- build f64 system into LDS (256 threads cooperative)
  for (int e = tid; e < NSYS * NCOL; e += 256) {
    const int r = e / NCOL, c = e - r * NCOL;
    M64[r][c] = sys_entry(r, c, s_dst, s_disp);
  }
  __syncthreads();

  // ---- f32 shard into named scalars: wave wv, columns cbase..cbase+18
  const int rowA = lane, rowB = lane + 64;
  const bool hasB = (rowB < NSYS);
  const int cbase = wv * SEG;
#define DCL(i) float gA##i, gB##i;
  REP19(DCL)
#undef DCL
#define BLD(i) { const int c = cbase + i;                                     \
    gA##i = (c < NCOL) ? (float)M64[rowA][c] : 0.0f;                          \
    gB##i = (hasB && c < NCOL) ? (float)M64[rowB][c] : 0.0f; }
  REP19(BLD)
#undef BLD

  // ---- f32 GE, no-swap partial pivoting, 1 barrier/step
  float cvA = gA0, cvB = gB0;   // shadow of current pivot column (owner wave uses)
  bool actA = true, actB = hasB;
  int slotA = 0, slotB = 0;

#pragma unroll 1
  for (int p = 0; p < NSYS; ++p) {
    const int buf = p & 1;
    if (wv == p / SEG) {   // owner wave: argmax + publish multipliers
      unsigned ua = actA ? ((__float_as_uint(fabsf(cvA)) & 0xFFFFFF80u) | (unsigned)rowA) : 0u;
      unsigned ub = actB ? ((__float_as_uint(fabsf(cvB)) & 0xFFFFFF80u) | (unsigned)rowB) : 0u;
      unsigned u = ua > ub ? ua : ub;
#pragma unroll
      for (int o = 1; o < 64; o <<= 1) {
        const unsigned v = __shfl_xor(u, o);
        if (v > u) u = v;
      }
      const int piv = (int)(u & 0x7Fu);
      const float pv = (piv < 64) ? rl_f32(cvA, piv) : rl_f32(cvB, piv - 64);
      const float inv = 1.0f / pv;
      const float mA = (actA && rowA != piv) ? cvA * inv : 0.0f;
      const float mB = (actB && rowB != piv) ? cvB * inv : 0.0f;
      Lm[p][lane] = mA;
      if (lane < 7) Lm[p][64 + lane] = mB;
      if (lane == 0) { s_piv[buf] = piv; s_perm[p] = piv; }
    }
    __syncthreads();
    const int piv = __builtin_amdgcn_readfirstlane(s_piv[buf]);
    if (piv == rowA) { actA = false; slotA = p; }
    if (hasB && piv == rowB) { actB = false; slotB = p; }
    // whole-shard skip once all owned columns are in the eliminated region
    if (cbase + SEG > p + 1) {
      const float myMA = Lm[p][lane];
      const float myMB = (lane < 7) ? Lm[p][64 + lane] : 0.0f;
      const int  pl = (piv < 64) ? piv : piv - 64;
      if (piv >= 64) {
#define UPDB(i) { const float pr = rl_f32(gB##i, pl); \
        gA##i = fmaf(-myMA, pr, gA##i); gB##i = fmaf(-myMB, pr, gB##i); }
        REP19(UPDB)
#undef UPDB
      } else {
#define UPDA(i) { const float pr = rl_f32(gA##i, pl); \
        gA##i = fmaf(-myMA, pr, gA##i); gB##i = fmaf(-myMB, pr, gB##i); }
        REP19(UPDA)
#undef UPDA
      }
      const int pn = p + 1;
#define XT(i) if (cbase + i == pn) { cvA = gA##i; cvB = gB##i; }
      REP19(XT)
#undef XT
    }
  }

  // ---- dump U by slot: Ud[col][slot]
#define DMP(i) { const int c = cbase + i; if (c < NCOL) {                     \
    Ud[c][slotA] = gA##i; if (hasB) Ud[c][slotB] = gB##i; } }
  REP19(DMP)
#undef DMP
  __syncthreads();

  // ---- back-sub (f64 accumulation over f32 U; slot == variable).
  // Run redundantly by ALL 4 waves (identical per-wave results) so that the
  // __syncthreads inside refinement is unconditional.
  double sol0a, sol1a, sol0b = 0.0, sol1b = 0.0;
  const double diA = 1.0 / (double)Ud[lane][lane];
  const double diB = hasB ? 1.0 / (double)Ud[rowB][rowB] : 1.0;
#define BACKSUB(BB0A, BB1A, BB0B, BB1B, O0A, O1A, O0B, O1B)                     \
  {                                                                             \
    double bb0a = (BB0A), bb1a = (BB1A), bb0b = (BB0B), bb1b = (BB1B);          \
    double acc0a = 0.0, acc1a = 0.0, acc0b = 0.0, acc1b = 0.0;                  \
    double s0a = 0.0, s1a = 0.0, s0b = 0.0, s1b = 0.0;                          \
    _Pragma("unroll 1")                                                         \
    for (int p = NSYS - 1; p >= 0; --p) {                                       \
      const double tA0 = (bb0a - acc0a) * diA;                                  \
      const double tA1 = (bb1a - acc1a) * diA;                                  \
      const double tB0 = (bb0b - acc0b) * diB;                                  \
      const double tB1 = (bb1b - acc1b) * diB;                                  \
      const bool fromB = (p >= 64);                                             \
      const int  src   = fromB ? (p - 64) : p;                                  \
      const double x0 = rl_f64(fromB ? tB0 : tA0, src);                         \
      const double x1 = rl_f64(fromB ? tB1 : tA1, src);                         \
      if (p >= 64) { if (lane == p - 64) { s0b = tB0; s1b = tB1; } }            \
      else         { if (lane == p)      { s0a = tA0; s1a = tA1; } }            \
      if (lane < p) {                                                           \
        const double u2 = (double)Ud[p][lane];                                  \
        acc0a = fma(u2, x0, acc0a);                                             \
        acc1a = fma(u2, x1, acc1a);                                             \
      }                                                                         \
      if (hasB && rowB < p) {                                                   \
        const double u2 = (double)Ud[p][rowB];                                  \
        acc0b = fma(u2, x0, acc0b);                                             \
        acc1b = fma(u2, x1, acc1b);                                             \
      }                                                                         \
    }                                                                           \
    O0A = s0a; O1A = s1a; O0B = s0b; O1B = s1b;                                 \
  }

  BACKSUB((double)Ud[NSYS][lane], (double)Ud[NSYS + 1][lane],
          hasB ? (double)Ud[NSYS][rowB] : 0.0, hasB ? (double)Ud[NSYS + 1][rowB] : 0.0,
          sol0a, sol1a, sol0b, sol1b)

  // ---- two mixed-precision refinement steps (f64 residual, f32 L/U solve)
#pragma unroll 1
  for (int it = 0; it < 2; ++it) {
    double r0A = M64[rowA][71], r1A = M64[rowA][72];
    double r0B = hasB ? M64[rowB][71] : 0.0;
    double r1B = hasB ? M64[rowB][72] : 0.0;
#pragma unroll 1
    for (int c = 0; c < 64; ++c) {
      const double x0 = rl_f64(sol0a, c), x1 = rl_f64(sol1a, c);
      const double a = M64[rowA][c];
      r0A = fma(-a, x0, r0A); r1A = fma(-a, x1, r1A);
      const double bm = hasB ? M64[rowB][c] : 0.0;
      r0B = fma(-bm, x0, r0B); r1B = fma(-bm, x1, r1B);
    }
#pragma unroll 1
    for (int c = 64; c < NSYS; ++c) {
      const double x0 = rl_f64(sol0b, c - 64), x1 = rl_f64(sol1b, c - 64);
      const double a = M64[rowA][c];
      r0A = fma(-a, x0, r0A); r1A = fma(-a, x1, r1A);
      const double bm = hasB ? M64[rowB][c] : 0.0;
      r0B = fma(-bm, x0, r0B); r1B = fma(-bm, x1, r1B);
    }
    // forward solve L*y = r (replay multipliers; frozen rows have m=0)
#pragma unroll 1
    for (int p = 0; p < NSYS; ++p) {
      const int pvv = __builtin_amdgcn_readfirstlane(s_perm[p]);
      const bool pB2 = pvv >= 64;
      const int  pl2 = pB2 ? pvv - 64 : pvv;
      const double yp0 = pB2 ? rl_f64(r0B, pl2) : rl_f64(r0A, pl2);
      const double yp1 = pB2 ? rl_f64(r1B, pl2) : rl_f64(r1A, pl2);
      const double lA = (double)Lm[p][lane];
      r0A = fma(-lA, yp0, r0A); r1A = fma(-lA, yp1, r1A);
      const double lB = (lane < 7) ? (double)Lm[p][64 + lane] : 0.0;
      r0B = fma(-lB, yp0, r0B); r1B = fma(-lB, yp1, r1B);
    }
    // re-gather y by slot (all waves write identical values — benign)
    yds0[rowA] = r0A; yds1[rowA] = r1A;
    if (hasB) { yds0[rowB] = r0B; yds1[rowB] = r1B; }
    __syncthreads();
    const int prA = s_perm[lane];
    const int prB = hasB ? s_perm[rowB] : 0;
    double d0a, d1a, d0b, d1b;
    BACKSUB(yds0[prA], yds1[prA],
            hasB ? yds0[prB] : 0.0, hasB ? yds1[prB] : 0.0,
            d0a, d1a, d0b, d1b)
    sol0a += d0a; sol1a += d1a; sol0b += d0b; sol1b += d1b;
    __syncthreads();
  }

  // ---- write solution (all waves write identical values — benign)
  ws[WS_WV + (size_t)b * 142 + 2 * rowA]     = (float)sol0a;
  ws[WS_WV + (size_t)b * 142 + 2 * rowA + 1] = (float)sol1a;
  if (hasB) {
    ws[WS_WV + (size_t)b * 142 + 2 * rowB]     = (float)sol0b;
    ws[WS_WV + (size_t)b * 142 + 2 * rowB + 1] = (float)sol1b;
  }
}

// ------------------------------- K3: fused spline eval + bilinear warp (+norm finalize)
__global__ __launch_bounds__(256) void k3_warp(const float* __restrict__ img,
                                               const float* __restrict__ ws,
                                               float* __restrict__ out) {
  const int orig = blockIdx.x;
  const int wgid = (orig & 7) * 256 + (orig >> 3);   // bijective (2048 % 8 == 0)
  const int b = wgid >> 8, y = wgid & 255;
  const int tid = threadIdx.x;   // = x

  if (orig == 0 && tid == 0) {
    float s = 0.f;
    for (int i = 0; i < NB; ++i) s += sqrtf(ws[WS_NORM + i]);
    out[OUT_NORM] = s * 0.125f;
  }

  __shared__ float s_c[NP], s_w[NP], s_v[6];
  if (tid < NP) {
    s_c[tid] = ws[WS_DST + b * NP + tid];
    s_w[tid] = ws[WS_WV + (size_t)b * 142 + tid];
  }
  if (tid >= NP && tid < NP + 6) s_v[tid - NP] = ws[WS_WV + (size_t)b * 142 + tid];
  __syncthreads();

  const float yf = (float)y, xf = (float)tid;
  float fy = fmaf(s_v[0], yf, fmaf(s_v[2], xf, s_v[4]));
  float fx = fmaf(s_v[1], yf, fmaf(s_v[3], xf, s_v[5]));
#pragma unroll 4
  for (int l = 0; l < NL; ++l) {
    const float dy = yf - s_c[2 * l];
    const float dx = xf - s_c[2 * l + 1];
    const float r  = fmaf(dy, dy, dx * dx);
    const float ph = 0.5f * r * __logf(fmaxf(r, 1e-10f));
    fy = fmaf(s_w[2 * l],     ph, fy);
    fx = fmaf(s_w[2 * l + 1], ph, fx);
  }

  const float qy = fminf(fmaxf(yf - fy, 0.f), 255.f);
  const float qx = fminf(fmaxf(xf - fx, 0.f), 255.f);
  int y0 = (int)floorf(qy); y0 = y0 > 254 ? 254 : y0;
  int x0 = (int)floorf(qx); x0 = x0 > 254 ? 254 : x0;
  const float wy = qy - (float)y0, wx = qx - (float)x0;
  const float w00 = (1.f - wy) * (1.f - wx), w01 = (1.f - wy) * wx;
  const float w10 = wy * (1.f - wx),         w11 = wy * wx;

  const float* p0 = img + (size_t)b * CIMG * 65536 + y0 * 256 + x0;
  const size_t ob = (size_t)b * CIMG * 65536 + (size_t)y * 256 + tid;
#pragma unroll 4
  for (int c = 0; c < CIMG; ++c) {
    const float* p = p0 + (size_t)c * 65536;
    const float v00 = p[0], v01 = p[1], v10 = p[256], v11 = p[257];
    const float val = fmaf(w00, v00, fmaf(w01, v01, fmaf(w10, v10, w11 * v11)));
    __builtin_nontemporal_store(val, &out[ob + (size_t)c * 65536]);
  }
}

// ------------------------------------------------------------------ launcher
extern "C" void kernel_launch(void* const* d_in, const int* in_sizes, int n_in,
                              void* d_out, int out_size, void* d_ws, size_t ws_size,
                              hipStream_t stream) {
  const float* x      = (const float*)d_in[0];
  const float* img    = (const float*)d_in[1];
  const float* scales = (const float*)d_in[2];
  const float* lmean  = (const float*)d_in[3];
  const float* W1     = (const float*)d_in[4];
  const float* b1     = (const float*)d_in[5];
  const float* W2     = (const float*)d_in[6];
  const float* b2     = (const float*)d_in[7];
  const float* W3     = (const float*)d_in[8];
  const float* b3     = (const float*)d_in[9];
  float* out = (float*)d_out;
  float* ws  = (float*)d_ws;

  k1_gemv<<<dim3(32, 32), 256, 0, stream>>>(x, W1, ws + WS_PART);
  k2_land_solve<<<NB, 256, 0, stream>>>(ws + WS_PART, scales, lmean, b1, W2, b2, W3, b3, out, ws);
  k3_warp<<<NB * HH, 256, 0, stream>>>(img, ws, out);
}